// Round 6
// baseline (286.883 us; speedup 1.0000x reference)
//
#include <hip/hip_runtime.h>
#include <hip/hip_cooperative_groups.h>
#include <math.h>

namespace cg = cooperative_groups;

#define BB 4
#define NN 2048
#define GG 1024
#define CC 3
#define MM 2049   // NN+1
#define SP 8      // G-splits for nearest
#define CH (GG / SP)
#define NBLK 256
#define NTHR 256

typedef unsigned long long u64;
#define KEY_EMPTY 0xFFFFFFFFFFFFFFFFULL

// ---------------- workspace layout ----------------
struct Ws {
  u64   near_key[BB * NN];    // (bits(dmin)<<32) | g  : per-point argmin over gts
  u64   best_key[BB * GG];    // (bits(dmin)<<32) | i  : per-gt argmin over points; EMPTY => none
  u64   keep_key[BB * NN];    // (bits(dist)<<32) | i  : surviving row for column j
  int   nearest[BB * NN];
  int   next_pred[BB * NN];
  int   col_cnt[BB * NN];
  int   nmax[BB];
  float cdist_sum[BB];
  float sem_sum[BB];
  float lossf_sum[BB];
  float lossb_sum[BB];
};

// position transform + pairwise distance, bit-matching XLA's sub->mul->add->sqrt
__device__ __forceinline__ float posx(float p) { return __fadd_rn(__fmul_rn(p, 0.15f), -29.925f); }
__device__ __forceinline__ float posy(float p) { return __fadd_rn(__fmul_rn(p, 0.15f), -14.925f); }
__device__ __forceinline__ float pdist(float ax, float ay, float bx, float by) {
  float dx = __fsub_rn(ax, bx);
  float dy = __fsub_rn(ay, by);
  return __fsqrt_rn(__fadd_rn(__fmul_rn(dx, dx), __fmul_rn(dy, dy)));
}
__device__ __forceinline__ u64 pack_key(float d, int i) {
  return ((u64)__float_as_uint(d) << 32) | (unsigned int)i;
}

// ---------------- the single cooperative kernel ----------------
__global__ __launch_bounds__(NTHR) void k_all(const float* __restrict__ matches,
                                              const float* __restrict__ positions,
                                              const float* __restrict__ semantics,
                                              const float* __restrict__ gt_pts,
                                              const int* __restrict__ gt_ins,
                                              const int* __restrict__ gt_type,
                                              Ws* ws, float* __restrict__ out, int out_size) {
  cg::grid_group grid = cg::this_grid();
  __shared__ int smem[2 * GG];               // 8 KB: phase1 uses 1 KB as floats; phase3 sins+sbest
  const int bid = blockIdx.x, tid = threadIdx.x;
  const int gtid = bid * NTHR + tid;
  const int NT = NBLK * NTHR;

  // ===== phase 0: zero d_out + init workspace =====
  {
    int n4 = out_size >> 2;
    float4 z = make_float4(0.f, 0.f, 0.f, 0.f);
    float4* o4 = reinterpret_cast<float4*>(out);
    for (int t = gtid; t < n4; t += NT) o4[t] = z;
    if (gtid < (out_size & 3)) out[n4 * 4 + gtid] = 0.f;
    if (gtid < BB * NN) {
      ws->near_key[gtid] = KEY_EMPTY;
      ws->keep_key[gtid] = KEY_EMPTY;
      ws->col_cnt[gtid] = 0;
    }
    if (gtid < BB * GG) ws->best_key[gtid] = KEY_EMPTY;
    if (gtid < BB) {
      ws->nmax[gtid] = 0;
      ws->cdist_sum[gtid] = 0.f;
      ws->sem_sum[gtid] = 0.f;
      ws->lossf_sum[gtid] = 0.f;
      ws->lossb_sum[gtid] = 0.f;
    }
  }
  grid.sync();

  // ===== phase 1: per-point argmin over a 128-gt chunk (packed atomicMin) =====
  // key = (bits(d)<<32)|g : lexicographic min == smallest d, ties -> smallest g
  // == jnp.argmin first-index tie-break.
  {
    int b = bid >> 6;                        // 64 blocks per batch
    int r = bid & 63;
    int i = (r >> 3) * NTHR + tid;           // 8 point-chunks of 256
    int g0 = (r & 7) * CH;                   // 8 gt-chunks of 128
    float* spts = reinterpret_cast<float*>(smem);
    spts[tid] = gt_pts[b * GG * 2 + g0 * 2 + tid];   // CH*2 == 256 floats
    __syncthreads();

    float px = posx(positions[(size_t)(b * NN + i) * 2 + 0]);
    float py = posy(positions[(size_t)(b * NN + i) * 2 + 1]);

    float dmin = INFINITY;
    int gmin = 0;
    #pragma unroll 4
    for (int g = 0; g < CH; ++g) {
      float d = pdist(px, py, spts[2 * g], spts[2 * g + 1]);
      if (d < dmin) { dmin = d; gmin = g; }  // strict < : first-index within chunk
    }
    atomicMin(&ws->near_key[b * NN + i], pack_key(dmin, g0 + gmin));
  }
  grid.sync();

  // ===== phase 2: unpack nearest, one-hot, sem gather, best_key, reductions =====
  if (bid < 128 && tid < 64) {               // 128 blocks x 1 wave
    int w = bid * 64 + tid;
    int b = w >> 11, i = w & (NN - 1);

    u64 key = ws->near_key[b * NN + i];
    float dmin = __uint_as_float((unsigned int)(key >> 32));
    int g = (int)(key & 0xFFFFFFFFULL);

    ws->nearest[b * NN + i] = g;
    atomicMin(&ws->best_key[b * GG + g], pack_key(dmin, i));  // cd[i,nearest[i]] == dmin

    int cls = gt_type[b * GG + g];
    float* sg = out + 3 + (size_t)BB * MM * MM;
    sg[(size_t)b * CC * NN + 0 * NN + i] = (cls == 0) ? 1.f : 0.f;
    sg[(size_t)b * CC * NN + 1 * NN + i] = (cls == 1) ? 1.f : 0.f;
    sg[(size_t)b * CC * NN + 2 * NN + i] = (cls == 2) ? 1.f : 0.f;
    float sem = semantics[(size_t)b * CC * NN + (size_t)cls * NN + i];

    float v = dmin;
    #pragma unroll
    for (int o = 32; o > 0; o >>= 1) v += __shfl_down(v, o, 64);
    if (tid == 0) atomicAdd(&ws->cdist_sum[b], v);

    v = sem;
    #pragma unroll
    for (int o = 32; o > 0; o >>= 1) v += __shfl_down(v, o, 64);
    if (tid == 0) atomicAdd(&ws->sem_sum[b], v);

    int m = g;
    #pragma unroll
    for (int o = 32; o > 0; o >>= 1) m = max(m, __shfl_down(m, o, 64));
    if (tid == 0) atomicMax(&ws->nmax[b], m);
  }
  grid.sync();

  // ===== phase 3: the jax.lax.while_loop walk + scatter-argmin for keep[] =====
  if (bid < 32) {                            // 32 blocks x 256 threads, 8 blocks/batch
    int w = bid * NTHR + tid;
    int b = w >> 11, i = w & (NN - 1);
    int* sins = smem;
    int* sbest = smem + GG;

    for (int t = tid; t < GG; t += NTHR) {
      sins[t] = gt_ins[b * GG + t];
      u64 k = ws->best_key[b * GG + t];
      sbest[t] = (k == KEY_EMPTY) ? -1 : (int)(k & 0xFFFFFFFFULL);
    }
    __syncthreads();

    int nmax = ws->nmax[b];
    int idx = ws->nearest[b * NN + i];
    int steps = 0, res = -1;
    while (true) {
      bool is_end = idx >= nmax;
      int gnr = is_end ? -1 : idx + 1;
      int gn = gnr & (GG - 1);               // jnp.mod for pow2 (handles -1 -> G-1)
      bool ex = (!is_end) && (sbest[gn] >= 0);
      bool same = sins[idx & (GG - 1)] == sins[gn];
      bool matched = ex && same;
      res = matched ? sbest[gn] : -1;
      bool stop = matched || (!same) || (steps >= GG + 2);
      idx = gnr;
      ++steps;
      if (stop) break;
    }
    ws->next_pred[b * NN + i] = res;
    if (res >= 0) {
      atomicAdd(&ws->col_cnt[b * NN + res], 1);
      const float* pb = positions + (size_t)b * NN * 2;
      float d = pdist(posx(pb[2 * i]), posy(pb[2 * i + 1]),
                      posx(pb[2 * res]), posy(pb[2 * res + 1]));
      atomicMin(&ws->keep_key[b * NN + res], pack_key(d, i));
    }
  }
  grid.sync();

  // ===== phase 4: A scatter + loss gathers/reductions =====
  if (bid < 128 && tid < 64) {
    int w = bid * 64 + tid;
    int b = w >> 11, i = w & (NN - 1);

    float* A = out + 3 + (size_t)b * MM * MM;

    int j = ws->next_pred[b * NN + i];
    bool surv = (j >= 0) && ((int)(ws->keep_key[b * NN + j] & 0xFFFFFFFFULL) == i);
    if (surv) A[(size_t)i * MM + j] = 1.0f;            // row i keeps its match
    else      A[(size_t)i * MM + (MM - 1)] = 1.0f;     // row fix: dustbin column

    int cnt = ws->col_cnt[b * NN + i];                 // i as column index
    if (cnt == 0) A[(size_t)(MM - 1) * MM + i] = 1.0f; // col fix: dustbin row

    // losses (tgt_f / tgt_b derived analytically)
    int tf = surv ? j : (MM - 1);
    float vf = matches[(size_t)b * MM * MM + (size_t)i * MM + tf];
    int tb = (cnt > 0) ? (int)(ws->keep_key[b * NN + i] & 0xFFFFFFFFULL) : (MM - 1);
    float vb = matches[(size_t)b * MM * MM + (size_t)i * MM + tb];

    float v = vf;
    #pragma unroll
    for (int o = 32; o > 0; o >>= 1) v += __shfl_down(v, o, 64);
    if (tid == 0) atomicAdd(&ws->lossf_sum[b], v);

    v = vb;
    #pragma unroll
    for (int o = 32; o > 0; o >>= 1) v += __shfl_down(v, o, 64);
    if (tid == 0) atomicAdd(&ws->lossb_sum[b], v);
  }
  grid.sync();

  // ===== phase 5: scalar finalize =====
  if (gtid == 0) {
    float cm = 0.f, ml = 0.f, sl = 0.f;
    for (int b = 0; b < BB; ++b) {
      cm += ws->cdist_sum[b] / (float)NN;
      float lf = -(ws->lossf_sum[b] / (float)(MM - 1));
      float lb = -(ws->lossb_sum[b] / (float)(MM - 1));
      ml += 0.5f * (lf + lb);
      sl += -(ws->sem_sum[b] / (float)NN);
    }
    out[0] = cm / (float)BB;
    out[1] = ml / (float)BB;
    out[2] = sl / (float)BB;
  }
}

// ---------------- launch ----------------
extern "C" void kernel_launch(void* const* d_in, const int* in_sizes, int n_in,
                              void* d_out, int out_size, void* d_ws, size_t ws_size,
                              hipStream_t stream) {
  (void)in_sizes; (void)n_in; (void)ws_size;
  const float* matches   = (const float*)d_in[0];
  const float* positions = (const float*)d_in[1];
  const float* semantics = (const float*)d_in[2];
  // d_in[3] = masks (unused by reference)
  const float* gt_pts    = (const float*)d_in[4];
  const int*   gt_ins    = (const int*)d_in[5];
  const int*   gt_type   = (const int*)d_in[6];
  float* out = (float*)d_out;
  Ws* ws = (Ws*)d_ws;
  int osz = out_size;

  void* args[] = {(void*)&matches, (void*)&positions, (void*)&semantics,
                  (void*)&gt_pts, (void*)&gt_ins, (void*)&gt_type,
                  (void*)&ws, (void*)&out, (void*)&osz};
  hipLaunchCooperativeKernel((const void*)k_all, dim3(NBLK), dim3(NTHR), args, 0, stream);
}

// Round 8
// 145.439 us; speedup vs baseline: 1.9725x; 1.9725x over previous
//
#include <hip/hip_runtime.h>
#include <math.h>

#define BB 4
#define NN 2048
#define GG 1024
#define CC 3
#define MM 2049                 // NN+1
#define ABEG 3                  // A starts at out[3]
#define ASZ (BB * MM * MM)      // 16793604
#define AEND (ABEG + ASZ)       // 16793607 ; sg follows
#define A4BEG 4                 // first 16B-aligned float in A region
#define NF4 ((AEND - A4BEG) / 4)  // 4198400 float4s, 3 scalar tail

typedef unsigned long long u64;
#define KEY_EMPTY 0xFFFFFFFFFFFFFFFFULL

// ---------------- workspace layout ----------------
struct Ws {
  u64   best_key[BB * GG];    // (bits(dmin)<<32) | i ; EMPTY => gt unassigned. memset 0xFF.
  int   nearest[BB * NN];
  float cdist_part[256];      // per-k_near-block partial sums (written, not accumulated)
  float sem_part[256];
  float lossf_sum[BB];
  float lossb_sum[BB];
};

// position transform + pairwise distance, bit-matching XLA's sub->mul->add->sqrt
__device__ __forceinline__ float posx(float p) { return __fadd_rn(__fmul_rn(p, 0.15f), -29.925f); }
__device__ __forceinline__ float posy(float p) { return __fadd_rn(__fmul_rn(p, 0.15f), -14.925f); }
__device__ __forceinline__ float pdist(float ax, float ay, float bx, float by) {
  float dx = __fsub_rn(ax, bx);
  float dy = __fsub_rn(ay, by);
  return __fsqrt_rn(__fadd_rn(__fmul_rn(dx, dx), __fmul_rn(dy, dy)));
}
__device__ __forceinline__ u64 pack_key(float d, int i) {
  return ((u64)__float_as_uint(d) << 32) | (unsigned int)i;
}

// ---------------- k_near: argmin over gts + one-hot + partials + embedded A-zero ----------------
// grid 256 = BB x 64 blocks; block = 32 points x 8 lanes. Lane q scans gts [128q,128q+128)
// in a rotated order (bank-conflict-free); packed (d,g) key keeps jnp.argmin first-index
// tie-break regardless of scan order. 8-lane __shfl_xor key-min combines.
__global__ __launch_bounds__(256) void k_near(const float* __restrict__ positions,
                                              const float* __restrict__ gt_pts,
                                              const int* __restrict__ gt_type,
                                              const float* __restrict__ semantics,
                                              Ws* ws, float* __restrict__ out) {
  __shared__ float spts[GG * 2];
  __shared__ float sdm[32], ssm[32];
  const int bid = blockIdx.x, tid = threadIdx.x;
  const int b = bid >> 6, blk = bid & 63;
  const int p = tid >> 3, q = tid & 7;
  const int i = blk * 32 + p;

  // stage all 1024 gt points (8 KB)
  {
    const float4* src = reinterpret_cast<const float4*>(gt_pts + b * GG * 2);
    float4* dst = reinterpret_cast<float4*>(spts);
    dst[tid] = src[tid];
    dst[tid + 256] = src[tid + 256];
  }
  // embedded zero of the A region: fire-and-forget stores drain under the scan
  {
    float4 z = make_float4(0.f, 0.f, 0.f, 0.f);
    float4* o4 = reinterpret_cast<float4*>(out + A4BEG);
    int gt = bid * 256 + tid;
    for (int t = gt; t < NF4; t += 256 * 256) o4[t] = z;
    if (gt == 3) out[ABEG] = 0.f;                 // unaligned head
    if (gt < 3) out[AEND - 3 + gt] = 0.f;         // tail scalars
  }
  __syncthreads();

  float2 pp = reinterpret_cast<const float2*>(positions)[b * NN + i];
  float px = posx(pp.x), py = posy(pp.y);

  u64 key = KEY_EMPTY;
  const int g0 = q * 128;
  #pragma unroll 4
  for (int k = 0; k < 128; ++k) {
    int o = (k + 2 * q) & 127;                    // rotation: 8 lanes hit 8 distinct bank pairs
    int g = g0 + o;
    float d = pdist(px, py, spts[2 * g], spts[2 * g + 1]);
    u64 kk = pack_key(d, g);
    key = kk < key ? kk : key;                    // (d,g) lexicographic min
  }
  #pragma unroll
  for (int m = 4; m > 0; m >>= 1) {
    u64 other = __shfl_xor(key, m, 64);           // partners stay within the 8-lane group
    key = other < key ? other : key;
  }

  if (q == 0) {
    float dmin = __uint_as_float((unsigned int)(key >> 32));
    int g = (int)(key & 0xFFFFFFFFULL);
    ws->nearest[b * NN + i] = g;
    atomicMin(&ws->best_key[b * GG + g], pack_key(dmin, i));  // cd[i,nearest[i]] == dmin

    int cls = gt_type[b * GG + g];
    float* sg = out + AEND;
    sg[(size_t)b * CC * NN + 0 * NN + i] = (cls == 0) ? 1.f : 0.f;
    sg[(size_t)b * CC * NN + 1 * NN + i] = (cls == 1) ? 1.f : 0.f;
    sg[(size_t)b * CC * NN + 2 * NN + i] = (cls == 2) ? 1.f : 0.f;
    sdm[p] = dmin;
    ssm[p] = semantics[(size_t)b * CC * NN + (size_t)cls * NN + i];
  }
  __syncthreads();
  if (tid < 32) {                                 // width-32 reduce (lanes 32+ hold garbage)
    float v1 = sdm[tid], v2 = ssm[tid];
    #pragma unroll
    for (int o = 16; o > 0; o >>= 1) {
      v1 += __shfl_down(v1, o, 32);
      v2 += __shfl_down(v2, o, 32);
    }
    if (tid == 0) { ws->cdist_part[bid] = v1; ws->sem_part[bid] = v2; }
  }
}

// ---------------- k_walkpost: walk + col_cnt/keep (LDS) + A scatter + losses ----------------
// one 1024-thread block per batch; 2 points per thread.
__global__ __launch_bounds__(1024) void k_walkpost(const int* __restrict__ gt_ins,
                                                   const float* __restrict__ positions,
                                                   const float* __restrict__ matches,
                                                   Ws* ws, float* __restrict__ out) {
  __shared__ int   sins[GG];
  __shared__ int   sbest[GG];
  __shared__ int   scnt[NN];
  __shared__ u64   skeep[NN];
  __shared__ int   snmax[16];
  __shared__ float swf[16], swb[16];
  const int b = blockIdx.x, tid = threadIdx.x;
  const int wv = tid >> 6, ln = tid & 63;

  if (tid < GG / 4)
    reinterpret_cast<int4*>(sins)[tid] = reinterpret_cast<const int4*>(gt_ins + b * GG)[tid];
  int cand;
  {
    u64 k = ws->best_key[b * GG + tid];           // 1 entry per thread
    int v = (k == KEY_EMPTY) ? -1 : (int)(k & 0xFFFFFFFFULL);
    sbest[tid] = v;
    cand = (v >= 0) ? tid : 0;                    // nmax = max{g : best_key[g] set} == nearest.max()
  }
  scnt[tid] = 0;         scnt[tid + 1024] = 0;
  skeep[tid] = KEY_EMPTY; skeep[tid + 1024] = KEY_EMPTY;
  #pragma unroll
  for (int o = 32; o > 0; o >>= 1) cand = max(cand, __shfl_down(cand, o, 64));
  if (ln == 0) snmax[wv] = cand;
  __syncthreads();
  int nmax = snmax[0];
  #pragma unroll
  for (int w = 1; w < 16; ++w) nmax = max(nmax, snmax[w]);

  const float* pb = positions + (size_t)b * NN * 2;

  int res[2];
  #pragma unroll
  for (int s = 0; s < 2; ++s) {
    int i = tid + s * 1024;
    int idx = ws->nearest[b * NN + i];
    int steps = 0, r = -1;
    while (true) {
      bool is_end = idx >= nmax;
      int gnr = is_end ? -1 : idx + 1;
      int gn = gnr & (GG - 1);                    // jnp.mod for pow2 (handles -1 -> G-1)
      bool ex = (!is_end) && (sbest[gn] >= 0);
      bool same = sins[idx & (GG - 1)] == sins[gn];
      bool matched = ex && same;
      r = matched ? sbest[gn] : -1;
      bool stop = matched || (!same) || (steps >= GG + 2);
      idx = gnr;
      ++steps;
      if (stop) break;
    }
    res[s] = r;
    if (r >= 0) {
      atomicAdd(&scnt[r], 1);
      float2 pi = reinterpret_cast<const float2*>(pb)[i];
      float2 pr = reinterpret_cast<const float2*>(pb)[r];
      float d = pdist(posx(pi.x), posy(pi.y), posx(pr.x), posy(pr.y));
      atomicMin(&skeep[r], pack_key(d, i));
    }
  }
  __syncthreads();

  float* A = out + ABEG + (size_t)b * MM * MM;
  const float* mb = matches + (size_t)b * MM * MM;
  float accf = 0.f, accb = 0.f;
  #pragma unroll
  for (int s = 0; s < 2; ++s) {
    int i = tid + s * 1024;
    int j = res[s];
    bool surv = (j >= 0) && ((int)(skeep[j] & 0xFFFFFFFFULL) == i);
    if (surv) A[(size_t)i * MM + j] = 1.0f;            // row i keeps its match
    else      A[(size_t)i * MM + (MM - 1)] = 1.0f;     // row fix: dustbin column
    int cnt = scnt[i];                                 // i as column index
    if (cnt == 0) A[(size_t)(MM - 1) * MM + i] = 1.0f; // col fix: dustbin row
    int tf = surv ? j : (MM - 1);
    accf += mb[(size_t)i * MM + tf];
    int tb = (cnt > 0) ? (int)(skeep[i] & 0xFFFFFFFFULL) : (MM - 1);
    accb += mb[(size_t)i * MM + tb];
  }
  #pragma unroll
  for (int o = 32; o > 0; o >>= 1) {
    accf += __shfl_down(accf, o, 64);
    accb += __shfl_down(accb, o, 64);
  }
  if (ln == 0) { swf[wv] = accf; swb[wv] = accb; }
  __syncthreads();
  if (tid == 0) {
    float sf = 0.f, sb = 0.f;
    #pragma unroll
    for (int w = 0; w < 16; ++w) { sf += swf[w]; sb += swb[w]; }
    ws->lossf_sum[b] = sf;
    ws->lossb_sum[b] = sb;
  }
}

// ---------------- k_final: combine partials, write 3 scalars ----------------
__global__ __launch_bounds__(256) void k_final(Ws* ws, float* __restrict__ out) {
  __shared__ float scd[4], ssm2[4];
  const int tid = threadIdx.x;
  const int w = tid >> 6, ln = tid & 63;            // wave w handles batch w (k_near bid = b*64+blk)
  float v1 = ws->cdist_part[w * 64 + ln];
  float v2 = ws->sem_part[w * 64 + ln];
  #pragma unroll
  for (int o = 32; o > 0; o >>= 1) {
    v1 += __shfl_down(v1, o, 64);
    v2 += __shfl_down(v2, o, 64);
  }
  if (ln == 0) { scd[w] = v1; ssm2[w] = v2; }
  __syncthreads();
  if (tid == 0) {
    float cm = 0.f, ml = 0.f, sl = 0.f;
    for (int b = 0; b < BB; ++b) {
      cm += scd[b] / (float)NN;
      float lf = -(ws->lossf_sum[b] / (float)(MM - 1));
      float lb = -(ws->lossb_sum[b] / (float)(MM - 1));
      ml += 0.5f * (lf + lb);
      sl += -(ssm2[b] / (float)NN);
    }
    out[0] = cm / (float)BB;
    out[1] = ml / (float)BB;
    out[2] = sl / (float)BB;
  }
}

// ---------------- launch: 4 graph nodes ----------------
extern "C" void kernel_launch(void* const* d_in, const int* in_sizes, int n_in,
                              void* d_out, int out_size, void* d_ws, size_t ws_size,
                              hipStream_t stream) {
  (void)in_sizes; (void)n_in; (void)ws_size; (void)out_size;
  const float* matches   = (const float*)d_in[0];
  const float* positions = (const float*)d_in[1];
  const float* semantics = (const float*)d_in[2];
  // d_in[3] = masks (unused by reference)
  const float* gt_pts    = (const float*)d_in[4];
  const int*   gt_ins    = (const int*)d_in[5];
  const int*   gt_type   = (const int*)d_in[6];
  float* out = (float*)d_out;
  Ws* ws = (Ws*)d_ws;

  hipMemsetAsync(ws, 0xFF, sizeof(u64) * BB * GG, stream);   // best_key = KEY_EMPTY
  k_near<<<BB * 64, 256, 0, stream>>>(positions, gt_pts, gt_type, semantics, ws, out);
  k_walkpost<<<BB, 1024, 0, stream>>>(gt_ins, positions, matches, ws, out);
  k_final<<<1, 256, 0, stream>>>(ws, out);
}